// Round 1
// baseline (713.691 us; speedup 1.0000x reference)
//
#include <hip/hip_runtime.h>
#include <cstdint>

// PassiveLayer muon scattering, fused single kernel.
// Must reproduce JAX threefry2x32 PRNG stream bit-exactly (see analysis):
//   base key = (0, 42); step key_i = threefry((0,42), (0, i))
//   zr[0][n],zr[2][n] = threefry(key_i, (n, n+2N)) words 0,1
//   zr[1][n],zr[3][n] = threefry(key_i, (N+n, 3N+n)) words 0,1

constexpr int   NSTEPS = 32;
constexpr float Z_TOP  = 1.0f;
constexpr float Z_BOT  = 0.9f;    // f32(1.0 - 0.1)
constexpr float LW     = 10.0f;
constexpr float VSIZE  = 0.1f;
constexpr float STEP   = 0.01f;
constexpr float COEF_A = 13.6e-3f;
constexpr float COEF_B = 0.038f;

__device__ __forceinline__ uint32_t rotl32(uint32_t v, int d) {
  return (v << d) | (v >> (32 - d));
}

// JAX threefry2x32 (20 rounds, 5 key injections) — matches jax/_src/prng.py
__device__ __forceinline__ void threefry2x32(uint32_t k0, uint32_t k1,
                                             uint32_t& x0, uint32_t& x1) {
  uint32_t k2 = k0 ^ k1 ^ 0x1BD11BDAu;
  x0 += k0; x1 += k1;
#define TF_R(r) { x0 += x1; x1 = rotl32(x1, r); x1 ^= x0; }
  TF_R(13) TF_R(15) TF_R(26) TF_R(6)
  x0 += k1; x1 += k2 + 1u;
  TF_R(17) TF_R(29) TF_R(16) TF_R(24)
  x0 += k2; x1 += k0 + 2u;
  TF_R(13) TF_R(15) TF_R(26) TF_R(6)
  x0 += k0; x1 += k1 + 3u;
  TF_R(17) TF_R(29) TF_R(16) TF_R(24)
  x0 += k1; x1 += k2 + 4u;
  TF_R(13) TF_R(15) TF_R(26) TF_R(6)
  x0 += k2; x1 += k0 + 5u;
#undef TF_R
}

// XLA f32 ErfInv (Giles polynomial) — matches xla math.cc coefficients.
__device__ __forceinline__ float erfinv_f32(float x) {
  float w = -log1pf(-x * x);
  float p;
  if (w < 5.0f) {
    w = w - 2.5f;
    p = 2.81022636e-08f;
    p = fmaf(p, w, 3.43273939e-07f);
    p = fmaf(p, w, -3.5233877e-06f);
    p = fmaf(p, w, -4.39150654e-06f);
    p = fmaf(p, w, 0.00021858087f);
    p = fmaf(p, w, -0.00125372503f);
    p = fmaf(p, w, -0.00417768164f);
    p = fmaf(p, w, 0.246640727f);
    p = fmaf(p, w, 1.50140941f);
  } else {
    w = sqrtf(w) - 3.0f;
    p = -0.000200214257f;
    p = fmaf(p, w, 0.000100950558f);
    p = fmaf(p, w, 0.00134934322f);
    p = fmaf(p, w, -0.00367342844f);
    p = fmaf(p, w, 0.00573950773f);
    p = fmaf(p, w, -0.0076224613f);
    p = fmaf(p, w, 0.00943887047f);
    p = fmaf(p, w, 1.00167406f);
    p = fmaf(p, w, 2.83297682f);
  }
  return p * x;
}

// jax.random.normal: u = uniform(bits, lo=nextafter(-1,0), hi=1); sqrt(2)*erfinv(u)
__device__ __forceinline__ float bits_to_normal(uint32_t bits) {
  uint32_t fb = (bits >> 9) | 0x3f800000u;
  float f = __uint_as_float(fb) - 1.0f;        // [0, 1)
  const float lo = -0.99999994f;               // nextafter(-1,0) in f32
  float u = f * 2.0f + lo;                     // (hi - lo) folds to 2.0f in f32 RN
  u = fmaxf(lo, u);
  return 1.41421356f * erfinv_f32(u);          // f32(sqrt(2)) = 0x3FB504F3
}

__global__ __launch_bounds__(256)
void passive_layer_kernel(const float* __restrict__ xin,
                          const float* __restrict__ yin,
                          const float* __restrict__ zin,
                          const float* __restrict__ txin,
                          const float* __restrict__ tyin,
                          const float* __restrict__ momin,
                          const float* __restrict__ rad,
                          float* __restrict__ out, int N) {
  __shared__ uint32_t skeys[NSTEPS * 2];
  if (threadIdx.x < NSTEPS) {
    uint32_t a = 0u, b = (uint32_t)threadIdx.x;
    threefry2x32(0u, 42u, a, b);   // fold_in(key(42), i)
    skeys[2 * threadIdx.x]     = a;
    skeys[2 * threadIdx.x + 1] = b;
  }
  __syncthreads();

  int n = blockIdx.x * blockDim.x + threadIdx.x;
  if (n >= N) return;

  float x = xin[n], y = yin[n], z = zin[n];
  float tx = txin[n], ty = tyin[n];
  float coef_over_p = COEF_A / momin[n];
  const uint32_t uN = (uint32_t)N;
  const uint32_t un = (uint32_t)n;

  // propagate to top of layer
  float dz0 = z - Z_TOP;
  x += dz0 * tanf(tx);
  y += dz0 * tanf(ty);
  z -= dz0;

#pragma unroll 1
  for (int i = 0; i < NSTEPS; ++i) {
    uint32_t k0 = skeys[2 * i], k1 = skeys[2 * i + 1];

    bool mask = (z > Z_BOT) && (z <= Z_TOP);
    float ttx = tanf(tx), tty = tanf(ty);
    float cos_th = rsqrtf(1.0f + ttx * ttx + tty * tty);

    bool smask = (x >= 0.0f) && (x < LW) && (y >= 0.0f) && (y < LW) && mask;
    int ix = (int)floorf(x / VSIZE); ix = min(max(ix, 0), 99);
    int iy = (int)floorf(y / VSIZE); iy = min(max(iy, 0), 99);
    float x0 = rad[ix * 100 + iy];

    float r_out = (z - Z_BOT) / cos_th;
    float step_len = fmaxf(fminf(STEP, r_out), 1e-9f);
    float n_x0 = step_len / x0;
    float theta0 = (coef_over_p * sqrtf(n_x0)) * (1.0f + COEF_B * logf(n_x0));

    // PRNG: two threefry evals give all four normals for this muon/step
    uint32_t a0 = un,      a1 = un + 2u * uN;
    threefry2x32(k0, k1, a0, a1);            // -> zr0, zr2
    uint32_t b0 = un + uN, b1 = un + 3u * uN;
    threefry2x32(k0, k1, b0, b1);            // -> zr1, zr3
    float z0 = bits_to_normal(a0);
    float z1 = bits_to_normal(b0);
    float z2 = bits_to_normal(a1);
    float z3 = bits_to_normal(b1);

    float dtx = theta0 * z0;
    float dty = theta0 * z1;
    float slt = step_len * theta0;
    float dxv = slt * (z2 / 3.4641016f + z0 * 0.5f);   // f32(sqrt(12))
    float dyv = slt * (z3 / 3.4641016f + z1 * 0.5f);

    if (smask) { x += dxv; y += dyv; }

    float dz = STEP * cos_th;
    if (mask) { x += dz * ttx; y += dz * tty; z -= dz; }

    float dzr = z - Z_BOT;
    bool em = (dzr < 0.0f) && mask;
    if (em) { x += dzr * ttx; y += dzr * tty; z -= dzr; }

    if (smask) { tx += dtx; ty += dty; }
  }

  // snap to bottom of layer
  float dz1 = z - Z_BOT;
  x += dz1 * tanf(tx);
  y += dz1 * tanf(ty);

  float4 o = make_float4(x, y, tx, ty);
  reinterpret_cast<float4*>(out)[n] = o;
}

extern "C" void kernel_launch(void* const* d_in, const int* in_sizes, int n_in,
                              void* d_out, int out_size, void* d_ws, size_t ws_size,
                              hipStream_t stream) {
  const float* x   = (const float*)d_in[0];
  const float* y   = (const float*)d_in[1];
  const float* z   = (const float*)d_in[2];
  const float* tx  = (const float*)d_in[3];
  const float* ty  = (const float*)d_in[4];
  const float* mom = (const float*)d_in[5];
  const float* rad = (const float*)d_in[6];
  float* out = (float*)d_out;
  int N = in_sizes[0];
  int block = 256;
  int grid = (N + block - 1) / block;
  passive_layer_kernel<<<grid, block, 0, stream>>>(x, y, z, tx, ty, mom, rad, out, N);
}

// Round 2
// 402.683 us; speedup vs baseline: 1.7723x; 1.7723x over previous
//
#include <hip/hip_runtime.h>
#include <cstdint>

// PassiveLayer muon scattering, fused single kernel.
// PRNG reproduces JAX threefry2x32 bit-exactly:
//   base key = (0, 42); step key_i = threefry((0,42), (0, i))
//   zr[0][n],zr[2][n] = threefry(key_i, (n, n+2N)) words 0,1
//   zr[1][n],zr[3][n] = threefry(key_i, (N+n, 3N+n)) words 0,1
//
// Numeric-risk policy (absmax margin vs threshold is ~0.1%):
//  - POSITION-critical ops (tanf, x/VSIZE voxel index, rsqrtf->dz, all
//    position-update add ordering) are kept bit-identical to the passing R1
//    kernel: they set the voxel-flip rate vs the np reference.
//  - theta0/z-draw paths are damped by x0.0136 before reaching positions, so
//    hw transcendentals (v_log/v_sqrt/v_rcp, ~2^-21 rel) are safe there.

constexpr int   NSTEPS = 32;
constexpr float Z_TOP  = 1.0f;
constexpr float Z_BOT  = 0.9f;
constexpr float LW     = 10.0f;
constexpr float VSIZE  = 0.1f;
constexpr float STEP   = 0.01f;
constexpr float COEF_A = 13.6e-3f;
constexpr float COEF_B = 0.038f;

__device__ __forceinline__ uint32_t rotl32(uint32_t v, int d) {
  return (v << d) | (v >> (32 - d));
}

// JAX threefry2x32 (20 rounds, 5 key injections)
__device__ __forceinline__ void threefry2x32(uint32_t k0, uint32_t k1,
                                             uint32_t& x0, uint32_t& x1) {
  uint32_t k2 = k0 ^ k1 ^ 0x1BD11BDAu;
  x0 += k0; x1 += k1;
#define TF_R(r) { x0 += x1; x1 = rotl32(x1, r); x1 ^= x0; }
  TF_R(13) TF_R(15) TF_R(26) TF_R(6)
  x0 += k1; x1 += k2 + 1u;
  TF_R(17) TF_R(29) TF_R(16) TF_R(24)
  x0 += k2; x1 += k0 + 2u;
  TF_R(13) TF_R(15) TF_R(26) TF_R(6)
  x0 += k0; x1 += k1 + 3u;
  TF_R(17) TF_R(29) TF_R(16) TF_R(24)
  x0 += k1; x1 += k2 + 4u;
  TF_R(13) TF_R(15) TF_R(26) TF_R(6)
  x0 += k2; x1 += k0 + 5u;
#undef TF_R
}

// XLA ErfInv polynomial (Giles), branchless two-chain; w via hw log of the
// exactly-rounded fma(-x,x,1). z-draw accuracy is damped by theta0 (~0.0136)
// before reaching positions, so ~1e-7 rel here is below the noise floor.
__device__ __forceinline__ float erfinv_fast(float x) {
  float w = -__logf(fmaf(x, -x, 1.0f));
  float ws = w - 2.5f;
  float p1 = 2.81022636e-08f;
  p1 = fmaf(p1, ws, 3.43273939e-07f);
  p1 = fmaf(p1, ws, -3.5233877e-06f);
  p1 = fmaf(p1, ws, -4.39150654e-06f);
  p1 = fmaf(p1, ws, 0.00021858087f);
  p1 = fmaf(p1, ws, -0.00125372503f);
  p1 = fmaf(p1, ws, -0.00417768164f);
  p1 = fmaf(p1, ws, 0.246640727f);
  p1 = fmaf(p1, ws, 1.50140941f);
  float wb = __builtin_amdgcn_sqrtf(w) - 3.0f;
  float p2 = -0.000200214257f;
  p2 = fmaf(p2, wb, 0.000100950558f);
  p2 = fmaf(p2, wb, 0.00134934322f);
  p2 = fmaf(p2, wb, -0.00367342844f);
  p2 = fmaf(p2, wb, 0.00573950773f);
  p2 = fmaf(p2, wb, -0.0076224613f);
  p2 = fmaf(p2, wb, 0.00943887047f);
  p2 = fmaf(p2, wb, 1.00167406f);
  p2 = fmaf(p2, wb, 2.83297682f);
  float p = (w < 5.0f) ? p1 : p2;
  return p * x;
}

// jax.random.normal bits->float path kept bit-identical (uniform mapping is
// exact); only erfinv internals are fast.
__device__ __forceinline__ float bits_to_normal(uint32_t bits) {
  uint32_t fb = (bits >> 9) | 0x3f800000u;
  float f = __uint_as_float(fb) - 1.0f;        // [0, 1)
  const float lo = -0.99999994f;               // nextafter(-1,0)
  float u = f * 2.0f + lo;                     // exact *2 -> fma-safe
  u = fmaxf(lo, u);
  return 1.41421356f * erfinv_fast(u);
}

__global__ __launch_bounds__(256)
void passive_layer_kernel(const float* __restrict__ xin,
                          const float* __restrict__ yin,
                          const float* __restrict__ zin,
                          const float* __restrict__ txin,
                          const float* __restrict__ tyin,
                          const float* __restrict__ momin,
                          const float* __restrict__ rad,
                          float* __restrict__ out, int N) {
  __shared__ uint32_t skeys[NSTEPS * 2];
  if (threadIdx.x < NSTEPS) {
    uint32_t a = 0u, b = (uint32_t)threadIdx.x;
    threefry2x32(0u, 42u, a, b);   // fold_in(key(42), i)
    skeys[2 * threadIdx.x]     = a;
    skeys[2 * threadIdx.x + 1] = b;
  }
  __syncthreads();

  int n = blockIdx.x * blockDim.x + threadIdx.x;
  if (n >= N) return;

  float x = xin[n], y = yin[n], z = zin[n];
  float tx = txin[n], ty = tyin[n];
  float coef_over_p = COEF_A / momin[n];
  const uint32_t uN = (uint32_t)N;
  const uint32_t un = (uint32_t)n;
  const uint32_t c0a = un,          c1a = un + 2u * uN;
  const uint32_t c0b = un + uN,     c1b = un + 3u * uN;

  // propagate to top of layer (position-critical: libm tanf)
  float dz0 = z - Z_TOP;
  x += dz0 * tanf(tx);
  y += dz0 * tanf(ty);
  z -= dz0;

#pragma unroll 1
  for (int i = 0; i < NSTEPS; ++i) {
    uint32_t k0 = skeys[2 * i], k1 = skeys[2 * i + 1];

    bool mask = (z > Z_BOT) && (z <= Z_TOP);
    float ttx = tanf(tx), tty = tanf(ty);          // position-critical: libm
    float s = 1.0f + ttx * ttx + tty * tty;
    float cos_th = rsqrtf(s);                      // position-critical (dz)

    bool smask = (x >= 0.0f) && (x < LW) && (y >= 0.0f) && (y < LW) && mask;
    int ix = (int)floorf(x / VSIZE); ix = min(max(ix, 0), 99);  // exact divide
    int iy = (int)floorf(y / VSIZE); iy = min(max(iy, 0), 99);
    float x0 = rad[ix * 100 + iy];

    // theta0 path: damped by ~0.0136 -> hw transcendentals are safe
    float r_out = (z - Z_BOT) * __builtin_amdgcn_sqrtf(s);     // was /cos_th
    float step_len = fmaxf(fminf(STEP, r_out), 1e-9f);
    float n_x0 = step_len * __builtin_amdgcn_rcpf(x0);         // was /x0
    float theta0 = (coef_over_p * __builtin_amdgcn_sqrtf(n_x0))
                 * fmaf(COEF_B, __logf(n_x0), 1.0f);

    uint32_t a0 = c0a, a1 = c1a;
    threefry2x32(k0, k1, a0, a1);            // -> zr0, zr2
    uint32_t b0 = c0b, b1 = c1b;
    threefry2x32(k0, k1, b0, b1);            // -> zr1, zr3
    float z0 = bits_to_normal(a0);
    float z1 = bits_to_normal(b0);
    float z2 = bits_to_normal(a1);
    float z3 = bits_to_normal(b1);

    float dtx = theta0 * z0;
    float dty = theta0 * z1;
    float slt = step_len * theta0;
    const float inv_s12 = 0.28867513459f;    // 1/sqrt(12), damped path
    float dxv = slt * (z2 * inv_s12 + z0 * 0.5f);
    float dyv = slt * (z3 * inv_s12 + z1 * 0.5f);

    // position updates: ordering kept bit-identical to R1
    if (smask) { x += dxv; y += dyv; }

    float dz = STEP * cos_th;
    if (mask) { x += dz * ttx; y += dz * tty; z -= dz; }

    float dzr = z - Z_BOT;
    bool em = (dzr < 0.0f) && mask;
    if (em) { x += dzr * ttx; y += dzr * tty; z -= dzr; }

    if (smask) { tx += dtx; ty += dty; }
  }

  // snap to bottom of layer
  float dz1 = z - Z_BOT;
  x += dz1 * tanf(tx);
  y += dz1 * tanf(ty);

  float4 o = make_float4(x, y, tx, ty);
  reinterpret_cast<float4*>(out)[n] = o;
}

extern "C" void kernel_launch(void* const* d_in, const int* in_sizes, int n_in,
                              void* d_out, int out_size, void* d_ws, size_t ws_size,
                              hipStream_t stream) {
  const float* x   = (const float*)d_in[0];
  const float* y   = (const float*)d_in[1];
  const float* z   = (const float*)d_in[2];
  const float* tx  = (const float*)d_in[3];
  const float* ty  = (const float*)d_in[4];
  const float* mom = (const float*)d_in[5];
  const float* rad = (const float*)d_in[6];
  float* out = (float*)d_out;
  int N = in_sizes[0];
  int block = 256;
  int grid = (N + block - 1) / block;
  passive_layer_kernel<<<grid, block, 0, stream>>>(x, y, z, tx, ty, mom, rad, out, N);
}

// Round 3
// 197.295 us; speedup vs baseline: 3.6174x; 2.0410x over previous
//
#include <hip/hip_runtime.h>
#include <cstdint>

// PassiveLayer muon scattering, fused single kernel.
// PRNG reproduces JAX threefry2x32 bit-exactly:
//   base key = (0, 42); step key_i = threefry((0,42), (0, i))
//   zr[0][n],zr[2][n] = threefry(key_i, (n, n+2N)) words 0,1
//   zr[1][n],zr[3][n] = threefry(key_i, (N+n, 3N+n)) words 0,1
//
// Numeric-risk policy (absmax 0.20224 vs threshold 0.2025, margin 0.13%):
//  - POSITION-critical ops (tanf, x/VSIZE voxel divide, rsqrtf->dz, update
//    ordering) bit-identical to the passing R1/R2 kernels: they set the
//    voxel-flip set vs the np reference.
//  - theta0/z-draw paths use hw transcendentals (validated in R2: absmax
//    bit-stable).
//  - R3: early wave-exit break (`!__any(mask)`) is BIT-EXACT: once a muon
//    exits, z == Z_BOT exactly (Sterbenz), mask stays false, and the whole
//    body is a masked no-op. Keys moved to a constexpr __constant__ table.

constexpr int   NSTEPS = 32;
constexpr float Z_TOP  = 1.0f;
constexpr float Z_BOT  = 0.9f;
constexpr float LW     = 10.0f;
constexpr float VSIZE  = 0.1f;
constexpr float STEP   = 0.01f;
constexpr float COEF_A = 13.6e-3f;
constexpr float COEF_B = 0.038f;

__host__ __device__ constexpr uint32_t rotl32c(uint32_t v, int d) {
  return (v << d) | (v >> (32 - d));
}

// JAX threefry2x32 (20 rounds, 5 key injections) — constexpr-capable.
template <typename U>
__host__ __device__ constexpr void threefry2x32(U k0, U k1, U& x0, U& x1) {
  U k2 = k0 ^ k1 ^ 0x1BD11BDAu;
  x0 += k0; x1 += k1;
#define TF_R(r) { x0 += x1; x1 = rotl32c(x1, r); x1 ^= x0; }
  TF_R(13) TF_R(15) TF_R(26) TF_R(6)
  x0 += k1; x1 += k2 + 1u;
  TF_R(17) TF_R(29) TF_R(16) TF_R(24)
  x0 += k2; x1 += k0 + 2u;
  TF_R(13) TF_R(15) TF_R(26) TF_R(6)
  x0 += k0; x1 += k1 + 3u;
  TF_R(17) TF_R(29) TF_R(16) TF_R(24)
  x0 += k1; x1 += k2 + 4u;
  TF_R(13) TF_R(15) TF_R(26) TF_R(6)
  x0 += k2; x1 += k0 + 5u;
#undef TF_R
}

// Per-step keys: fold_in(key(42), i) = threefry((0,42), (0,i)) — compile-time.
struct KeyTab { uint32_t a[NSTEPS]; uint32_t b[NSTEPS]; };
constexpr KeyTab make_keys() {
  KeyTab t{};
  for (int i = 0; i < NSTEPS; ++i) {
    uint32_t x0 = 0u, x1 = (uint32_t)i;
    threefry2x32(0u, 42u, x0, x1);
    t.a[i] = x0; t.b[i] = x1;
  }
  return t;
}
__device__ __constant__ KeyTab SKEYS = make_keys();

// XLA ErfInv polynomial (Giles), branchless two-chain; damped path.
__device__ __forceinline__ float erfinv_fast(float x) {
  float w = -__logf(fmaf(x, -x, 1.0f));
  float ws = w - 2.5f;
  float p1 = 2.81022636e-08f;
  p1 = fmaf(p1, ws, 3.43273939e-07f);
  p1 = fmaf(p1, ws, -3.5233877e-06f);
  p1 = fmaf(p1, ws, -4.39150654e-06f);
  p1 = fmaf(p1, ws, 0.00021858087f);
  p1 = fmaf(p1, ws, -0.00125372503f);
  p1 = fmaf(p1, ws, -0.00417768164f);
  p1 = fmaf(p1, ws, 0.246640727f);
  p1 = fmaf(p1, ws, 1.50140941f);
  float wb = __builtin_amdgcn_sqrtf(w) - 3.0f;
  float p2 = -0.000200214257f;
  p2 = fmaf(p2, wb, 0.000100950558f);
  p2 = fmaf(p2, wb, 0.00134934322f);
  p2 = fmaf(p2, wb, -0.00367342844f);
  p2 = fmaf(p2, wb, 0.00573950773f);
  p2 = fmaf(p2, wb, -0.0076224613f);
  p2 = fmaf(p2, wb, 0.00943887047f);
  p2 = fmaf(p2, wb, 1.00167406f);
  p2 = fmaf(p2, wb, 2.83297682f);
  float p = (w < 5.0f) ? p1 : p2;
  return p * x;
}

__device__ __forceinline__ float bits_to_normal(uint32_t bits) {
  uint32_t fb = (bits >> 9) | 0x3f800000u;
  float f = __uint_as_float(fb) - 1.0f;        // [0, 1)
  const float lo = -0.99999994f;               // nextafter(-1,0)
  float u = f * 2.0f + lo;
  u = fmaxf(lo, u);
  return 1.41421356f * erfinv_fast(u);
}

__global__ __launch_bounds__(256)
void passive_layer_kernel(const float* __restrict__ xin,
                          const float* __restrict__ yin,
                          const float* __restrict__ zin,
                          const float* __restrict__ txin,
                          const float* __restrict__ tyin,
                          const float* __restrict__ momin,
                          const float* __restrict__ rad,
                          float* __restrict__ out, int N) {
  int n = blockIdx.x * blockDim.x + threadIdx.x;
  if (n >= N) return;

  float x = xin[n], y = yin[n], z = zin[n];
  float tx = txin[n], ty = tyin[n];
  float coef_over_p = COEF_A / momin[n];
  const uint32_t uN = (uint32_t)N;
  const uint32_t un = (uint32_t)n;
  const uint32_t c0a = un,      c1a = un + 2u * uN;
  const uint32_t c0b = un + uN, c1b = un + 3u * uN;

  // propagate to top of layer (position-critical: libm tanf)
  float dz0 = z - Z_TOP;
  x += dz0 * tanf(tx);
  y += dz0 * tanf(ty);
  z -= dz0;

#pragma unroll 1
  for (int i = 0; i < NSTEPS; ++i) {
    bool mask = (z > Z_BOT) && (z <= Z_TOP);
    // BIT-EXACT early exit: once z==Z_BOT (exact snap), the body is a no-op
    // for that lane forever; if no lane is alive the remaining iterations
    // do nothing at all.
    if (!__any(mask)) break;

    // Issue the scattered gather first so its latency hides under the
    // independent threefry/erfinv work.
    bool smask = (x >= 0.0f) && (x < LW) && (y >= 0.0f) && (y < LW) && mask;
    int ix = (int)floorf(x / VSIZE); ix = min(max(ix, 0), 99);  // exact divide
    int iy = (int)floorf(y / VSIZE); iy = min(max(iy, 0), 99);
    float x0 = rad[ix * 100 + iy];

    uint32_t k0 = SKEYS.a[i], k1 = SKEYS.b[i];   // scalar (wave-uniform) loads
    uint32_t a0 = c0a, a1 = c1a;
    threefry2x32(k0, k1, a0, a1);            // -> zr0, zr2
    uint32_t b0 = c0b, b1 = c1b;
    threefry2x32(k0, k1, b0, b1);            // -> zr1, zr3

    float ttx = tanf(tx), tty = tanf(ty);    // position-critical: libm
    float s = 1.0f + ttx * ttx + tty * tty;
    float cos_th = rsqrtf(s);                // position-critical (dz)

    // theta0 path: damped by ~0.0136 -> hw transcendentals safe (R2-validated)
    float r_out = (z - Z_BOT) * __builtin_amdgcn_sqrtf(s);
    float step_len = fmaxf(fminf(STEP, r_out), 1e-9f);
    float n_x0 = step_len * __builtin_amdgcn_rcpf(x0);
    float theta0 = (coef_over_p * __builtin_amdgcn_sqrtf(n_x0))
                 * fmaf(COEF_B, __logf(n_x0), 1.0f);

    float z0 = bits_to_normal(a0);
    float z1 = bits_to_normal(b0);
    float z2 = bits_to_normal(a1);
    float z3 = bits_to_normal(b1);

    float dtx = theta0 * z0;
    float dty = theta0 * z1;
    float slt = step_len * theta0;
    const float inv_s12 = 0.28867513459f;    // 1/sqrt(12), damped path
    float dxv = slt * (z2 * inv_s12 + z0 * 0.5f);
    float dyv = slt * (z3 * inv_s12 + z1 * 0.5f);

    // position updates: ordering bit-identical to R1/R2
    if (smask) { x += dxv; y += dyv; }

    float dz = STEP * cos_th;
    if (mask) { x += dz * ttx; y += dz * tty; z -= dz; }

    float dzr = z - Z_BOT;
    bool em = (dzr < 0.0f) && mask;
    if (em) { x += dzr * ttx; y += dzr * tty; z -= dzr; }

    if (smask) { tx += dtx; ty += dty; }
  }

  // snap to bottom of layer
  float dz1 = z - Z_BOT;
  x += dz1 * tanf(tx);
  y += dz1 * tanf(ty);

  float4 o = make_float4(x, y, tx, ty);
  reinterpret_cast<float4*>(out)[n] = o;
}

extern "C" void kernel_launch(void* const* d_in, const int* in_sizes, int n_in,
                              void* d_out, int out_size, void* d_ws, size_t ws_size,
                              hipStream_t stream) {
  const float* x   = (const float*)d_in[0];
  const float* y   = (const float*)d_in[1];
  const float* z   = (const float*)d_in[2];
  const float* tx  = (const float*)d_in[3];
  const float* ty  = (const float*)d_in[4];
  const float* mom = (const float*)d_in[5];
  const float* rad = (const float*)d_in[6];
  float* out = (float*)d_out;
  int N = in_sizes[0];
  int block = 256;
  int grid = (N + block - 1) / block;
  passive_layer_kernel<<<grid, block, 0, stream>>>(x, y, z, tx, ty, mom, rad, out, N);
}

// Round 4
// 192.195 us; speedup vs baseline: 3.7134x; 1.0265x over previous
//
#include <hip/hip_runtime.h>
#include <cstdint>

// PassiveLayer muon scattering, fused single kernel.
// PRNG reproduces JAX threefry2x32 bit-exactly:
//   base key = (0, 42); step key_i = threefry((0,42), (0, i))
//   zr[0][n],zr[2][n] = threefry(key_i, (n, n+2N)) words 0,1
//   zr[1][n],zr[3][n] = threefry(key_i, (N+n, 3N+n)) words 0,1
//
// Numeric-risk policy (absmax 0.20224 vs threshold 0.2025, margin 0.13%):
//  - POSITION-critical ops (libm tanf, x/VSIZE voxel divide, rsqrtf->dz,
//    update expression shapes) identical to the passing R1-R3 kernels:
//    they set the voxel-flip set vs the np reference. DO NOT TOUCH.
//  - theta0/z-draw path (damped by ~0.0136) uses hw transcendentals; R2
//    proved ~1ulp perturbations there leave absmax bit-stable.
//  - R3: early wave-exit break is bit-exact (z snaps exactly to Z_BOT).
//  - R4: (a) masked updates as selects on deltas (matches the reference
//    where()-formula exactly; same expression shapes -> same contraction);
//    (b) wave-uniform skip of erfinv chain-2 (bit-exact: reference selects
//    chain-1 when w<5); (c) sqrt(2) folded into erfinv coeffs (damped path).

constexpr int   NSTEPS = 32;
constexpr float Z_TOP  = 1.0f;
constexpr float Z_BOT  = 0.9f;
constexpr float LW     = 10.0f;
constexpr float VSIZE  = 0.1f;
constexpr float STEP   = 0.01f;
constexpr float COEF_A = 13.6e-3f;
constexpr float COEF_B = 0.038f;

__host__ __device__ constexpr uint32_t rotl32c(uint32_t v, int d) {
  return (v << d) | (v >> (32 - d));
}

// JAX threefry2x32 (20 rounds, 5 key injections) — constexpr-capable.
template <typename U>
__host__ __device__ constexpr void threefry2x32(U k0, U k1, U& x0, U& x1) {
  U k2 = k0 ^ k1 ^ 0x1BD11BDAu;
  x0 += k0; x1 += k1;
#define TF_R(r) { x0 += x1; x1 = rotl32c(x1, r); x1 ^= x0; }
  TF_R(13) TF_R(15) TF_R(26) TF_R(6)
  x0 += k1; x1 += k2 + 1u;
  TF_R(17) TF_R(29) TF_R(16) TF_R(24)
  x0 += k2; x1 += k0 + 2u;
  TF_R(13) TF_R(15) TF_R(26) TF_R(6)
  x0 += k0; x1 += k1 + 3u;
  TF_R(17) TF_R(29) TF_R(16) TF_R(24)
  x0 += k1; x1 += k2 + 4u;
  TF_R(13) TF_R(15) TF_R(26) TF_R(6)
  x0 += k2; x1 += k0 + 5u;
#undef TF_R
}

// Per-step keys: fold_in(key(42), i) = threefry((0,42), (0,i)) — compile-time.
struct KeyTab { uint32_t a[NSTEPS]; uint32_t b[NSTEPS]; };
constexpr KeyTab make_keys() {
  KeyTab t{};
  for (int i = 0; i < NSTEPS; ++i) {
    uint32_t x0 = 0u, x1 = (uint32_t)i;
    threefry2x32(0u, 42u, x0, x1);
    t.a[i] = x0; t.b[i] = x1;
  }
  return t;
}
__device__ __constant__ KeyTab SKEYS = make_keys();

// bits -> uniform u in [nextafter(-1,0), 1)  (bit-identical to jax mapping)
__device__ __forceinline__ float bits_to_uniform(uint32_t bits) {
  uint32_t fb = (bits >> 9) | 0x3f800000u;
  float f = __uint_as_float(fb) - 1.0f;        // [0, 1)
  const float lo = -0.99999994f;               // nextafter(-1,0)
  float u = f * 2.0f + lo;
  return fmaxf(lo, u);
}

// XLA ErfInv chain-1 polynomial with sqrt(2) pre-folded into coefficients.
// (damped path: <=1ulp vs mul-by-sqrt2 afterwards; R2-validated safe)
__device__ __forceinline__ float erfinv_p1_s2(float w) {
  float ws = w - 2.5f;
  float p = 3.9742775e-08f;
  p = fmaf(p, ws, 4.8546373e-07f);
  p = fmaf(p, ws, -4.9828418e-06f);
  p = fmaf(p, ws, -6.2105426e-06f);
  p = fmaf(p, ws, 3.0912074e-04f);
  p = fmaf(p, ws, -1.7730442e-03f);
  p = fmaf(p, ws, -5.9081479e-03f);
  p = fmaf(p, ws, 3.4880632e-01f);
  p = fmaf(p, ws, 2.1233167e+00f);
  return p;
}
// chain-2 (w >= 5), sqrt(2)-folded
__device__ __forceinline__ float erfinv_p2_s2(float w) {
  float wb = __builtin_amdgcn_sqrtf(w) - 3.0f;
  float p = -2.8314768e-04f;
  p = fmaf(p, wb, 1.4276574e-04f);
  p = fmaf(p, wb, 1.9082629e-03f);
  p = fmaf(p, wb, -5.1950087e-03f);
  p = fmaf(p, wb, 8.1169428e-03f);
  p = fmaf(p, wb, -1.0779867e-02f);
  p = fmaf(p, wb, 1.3348557e-02f);
  p = fmaf(p, wb, 1.4165801e+00f);
  p = fmaf(p, wb, 4.0060855e+00f);
  return p;
}

__global__ __launch_bounds__(256)
void passive_layer_kernel(const float* __restrict__ xin,
                          const float* __restrict__ yin,
                          const float* __restrict__ zin,
                          const float* __restrict__ txin,
                          const float* __restrict__ tyin,
                          const float* __restrict__ momin,
                          const float* __restrict__ rad,
                          float* __restrict__ out, int N) {
  int n = blockIdx.x * blockDim.x + threadIdx.x;
  if (n >= N) return;

  float x = xin[n], y = yin[n], z = zin[n];
  float tx = txin[n], ty = tyin[n];
  float coef_over_p = COEF_A / momin[n];
  const uint32_t uN = (uint32_t)N;
  const uint32_t un = (uint32_t)n;
  const uint32_t c0a = un,      c1a = un + 2u * uN;
  const uint32_t c0b = un + uN, c1b = un + 3u * uN;

  // propagate to top of layer (position-critical: libm tanf)
  float dz0 = z - Z_TOP;
  x += dz0 * tanf(tx);
  y += dz0 * tanf(ty);
  z -= dz0;

#pragma unroll 1
  for (int i = 0; i < NSTEPS; ++i) {
    bool mask = (z > Z_BOT) && (z <= Z_TOP);
    // BIT-EXACT early exit: once z==Z_BOT (exact snap), the lane's body is a
    // no-op forever; when no lane is alive the rest of the loop does nothing.
    if (!__any(mask)) break;

    // Scattered gather first so latency hides under threefry/erfinv work.
    bool smask = (x >= 0.0f) && (x < LW) && (y >= 0.0f) && (y < LW) && mask;
    int ix = (int)floorf(x / VSIZE); ix = min(max(ix, 0), 99);  // exact divide
    int iy = (int)floorf(y / VSIZE); iy = min(max(iy, 0), 99);
    float x0 = rad[ix * 100 + iy];

    uint32_t k0 = SKEYS.a[i], k1 = SKEYS.b[i];   // wave-uniform scalar loads
    uint32_t a0 = c0a, a1 = c1a;
    threefry2x32(k0, k1, a0, a1);            // -> zr0, zr2
    uint32_t b0 = c0b, b1 = c1b;
    threefry2x32(k0, k1, b0, b1);            // -> zr1, zr3

    float ttx = tanf(tx), tty = tanf(ty);    // position-critical: libm
    float s = 1.0f + ttx * ttx + tty * tty;
    float cos_th = rsqrtf(s);                // position-critical (dz)

    // theta0 path: damped by ~0.0136 -> hw transcendentals safe (R2-validated)
    float r_out = (z - Z_BOT) * __builtin_amdgcn_sqrtf(s);
    float step_len = fmaxf(fminf(STEP, r_out), 1e-9f);
    float n_x0 = step_len * __builtin_amdgcn_rcpf(x0);
    float theta0 = (coef_over_p * __builtin_amdgcn_sqrtf(n_x0))
                 * fmaf(COEF_B, __logf(n_x0), 1.0f);

    // normals: u -> w -> poly; chain-2 only if some lane needs it (bit-exact)
    float u0 = bits_to_uniform(a0);
    float u1 = bits_to_uniform(b0);
    float u2 = bits_to_uniform(a1);
    float u3 = bits_to_uniform(b1);
    float w0 = -__logf(fmaf(u0, -u0, 1.0f));
    float w1 = -__logf(fmaf(u1, -u1, 1.0f));
    float w2 = -__logf(fmaf(u2, -u2, 1.0f));
    float w3 = -__logf(fmaf(u3, -u3, 1.0f));
    float p0 = erfinv_p1_s2(w0);
    float p1 = erfinv_p1_s2(w1);
    float p2 = erfinv_p1_s2(w2);
    float p3 = erfinv_p1_s2(w3);
    float wmax = fmaxf(fmaxf(w0, w1), fmaxf(w2, w3));
    if (__any(wmax >= 5.0f)) {               // ~58% of waves
      p0 = (w0 < 5.0f) ? p0 : erfinv_p2_s2(w0);
      p1 = (w1 < 5.0f) ? p1 : erfinv_p2_s2(w1);
      p2 = (w2 < 5.0f) ? p2 : erfinv_p2_s2(w2);
      p3 = (w3 < 5.0f) ? p3 : erfinv_p2_s2(w3);
    }
    float z0 = p0 * u0;                      // sqrt(2) already folded in
    float z1 = p1 * u1;
    float z2 = p2 * u2;
    float z3 = p3 * u3;

    float dtx = theta0 * z0;
    float dty = theta0 * z1;
    float slt = step_len * theta0;
    const float inv_s12 = 0.28867513459f;    // 1/sqrt(12), damped path
    float dxv = slt * (z2 * inv_s12 + z0 * 0.5f);
    float dyv = slt * (z3 * inv_s12 + z1 * 0.5f);

    // Position updates as selects on deltas — literally the reference
    // where()-formula; same expression shapes as R1-R3 (contraction-safe).
    float dxvm = smask ? dxv : 0.0f;
    float dyvm = smask ? dyv : 0.0f;
    x += dxvm;
    y += dyvm;

    float dz  = STEP * cos_th;
    float dzm = mask ? dz : 0.0f;
    x += dzm * ttx;
    y += dzm * tty;
    z -= dzm;

    float dzr  = z - Z_BOT;
    bool  em   = (dzr < 0.0f) && mask;
    float dzrm = em ? dzr : 0.0f;
    x += dzrm * ttx;
    y += dzrm * tty;
    z -= dzrm;

    float dtxm = smask ? dtx : 0.0f;
    float dtym = smask ? dty : 0.0f;
    tx += dtxm;
    ty += dtym;
  }

  // snap to bottom of layer
  float dz1 = z - Z_BOT;
  x += dz1 * tanf(tx);
  y += dz1 * tanf(ty);

  float4 o = make_float4(x, y, tx, ty);
  reinterpret_cast<float4*>(out)[n] = o;
}

extern "C" void kernel_launch(void* const* d_in, const int* in_sizes, int n_in,
                              void* d_out, int out_size, void* d_ws, size_t ws_size,
                              hipStream_t stream) {
  const float* x   = (const float*)d_in[0];
  const float* y   = (const float*)d_in[1];
  const float* z   = (const float*)d_in[2];
  const float* tx  = (const float*)d_in[3];
  const float* ty  = (const float*)d_in[4];
  const float* mom = (const float*)d_in[5];
  const float* rad = (const float*)d_in[6];
  float* out = (float*)d_out;
  int N = in_sizes[0];
  int block = 256;
  int grid = (N + block - 1) / block;
  passive_layer_kernel<<<grid, block, 0, stream>>>(x, y, z, tx, ty, mom, rad, out, N);
}